// Round 6
// baseline (260.422 us; speedup 1.0000x reference)
//
#include <hip/hip_runtime.h>
#include <hip/hip_bf16.h>

#define D_MODEL 4096
#define VOCAB 50257
#define NUM_SEQS 32
#define NT 1571   // ceil(VOCAB/32) vocab tiles of 32 rows
#define KW 2048   // K per wave (2 waves split K)
#define TSTEPS (KW / 16)  // 128

typedef __attribute__((ext_vector_type(8))) short bf16x8;
typedef __attribute__((ext_vector_type(16))) float f32x16;

// ws layout:
//   [0,128)              idx[32] int
//   [512, +256)          gkeys[32] u64 (global argmax keys, atomicMax)
//   [4096, +256KB)       hBh [512][32][8] short  (h hi bf16, MFMA-B-frag order)
//   [266240, +256KB)     hBl [512][32][8] short  (h lo bf16)

__device__ __forceinline__ void cvt2(float f, short* hi, short* lo) {
  union { __hip_bfloat16 b; short s; } h, l;
  h.b = __float2bfloat16(f);                 // RNE
  float hf = __bfloat162float(h.b);
  l.b = __float2bfloat16(f - hf);            // residual, RNE
  *hi = h.s; *lo = l.s;
}

__global__ void k_prep(const int* __restrict__ lens, int* __restrict__ idx,
                       unsigned long long* __restrict__ gkeys) {
  int t = threadIdx.x;
  if (t == 0) {
    int run = 0;
    for (int s = 0; s < NUM_SEQS; ++s) { run += lens[s]; idx[s] = run - 1; }
  }
  if (t < NUM_SEQS) gkeys[t] = 0ull;
}

// 256 blocks x 512: thread g -> (s = g>>12, k = g&4095). Coalesced hs reads.
__global__ void k_gather(const float* __restrict__ hs, const int* __restrict__ idx,
                         short* __restrict__ hBh, short* __restrict__ hBl) {
  int g = blockIdx.x * 512 + threadIdx.x;
  int s = g >> 12, k = g & 4095;
  float v = hs[(size_t)idx[s] * D_MODEL + k];
  short hi, lo; cvt2(v, &hi, &lo);
  int off = ((k >> 3) * 32 + s) * 8 + (k & 7);  // [k/8][s][k%8]
  hBh[off] = hi; hBl[off] = lo;
}

// grid NT x 128 (2 waves). Wave wv covers K [wv*2048, +2048) of one
// 32-vocab x 32-seq tile. A (W rows) converted f32->bf16 hi/lo in-register;
// B (h) from precomputed hi/lo planes (L2-hot). A-prefetch depth 3.
// Partials combined via LDS (fixed order -> deterministic), then per-seq
// key -> device atomicMax (commutative -> deterministic).
__global__ __launch_bounds__(128) void k_mfma(const float* __restrict__ W,
    const short* __restrict__ hBh, const short* __restrict__ hBl,
    unsigned long long* __restrict__ gkeys) {
  const int lane = threadIdx.x & 63;
  const int wv = threadIdx.x >> 6;
  const int half = lane >> 5;
  const int r32 = lane & 31;
  const int tile = blockIdx.x;
  const int wrow = min(tile * 32 + r32, VOCAB - 1);
  const int k0 = wv * KW;
  const float4* wr = (const float4*)(W + (size_t)wrow * D_MODEL + k0 + half * 8);
  const short* bph = hBh + (((size_t)(k0 >> 3) + half) * 32 + r32) * 8;
  const short* bpl = hBl + (((size_t)(k0 >> 3) + half) * 32 + r32) * 8;

  f32x16 accA, accB;
#pragma unroll
  for (int i = 0; i < 16; ++i) { accA[i] = 0.f; accB[i] = 0.f; }

  // A depth-3 prefetch (HBM stream), B depth-2 (L2 stream)
  float4 a0 = wr[0], a1 = wr[1];
  float4 b0 = wr[4], b1 = wr[5];
  float4 c0 = wr[8], c1 = wr[9];
  bf16x8 bh = *(const bf16x8*)(bph);
  bf16x8 bl = *(const bf16x8*)(bpl);

#pragma unroll 1
  for (int t = 0; t < TSTEPS; ++t) {
    const int t3 = (t + 3 < TSTEPS) ? t + 3 : 0;
    const int t1 = (t + 1 < TSTEPS) ? t + 1 : 0;
    float4 d0 = wr[4 * t3], d1 = wr[4 * t3 + 1];
    bf16x8 nbh = *(const bf16x8*)(bph + 512 * t1);
    bf16x8 nbl = *(const bf16x8*)(bpl + 512 * t1);

    float fa[8] = {a0.x, a0.y, a0.z, a0.w, a1.x, a1.y, a1.z, a1.w};
    bf16x8 ahi, alo;
#pragma unroll
    for (int e = 0; e < 8; ++e) {
      short hi, lo; cvt2(fa[e], &hi, &lo);
      ahi[e] = hi; alo[e] = lo;
    }

    accA = __builtin_amdgcn_mfma_f32_32x32x16_bf16(ahi, bh, accA, 0, 0, 0);
    accB = __builtin_amdgcn_mfma_f32_32x32x16_bf16(ahi, bl, accB, 0, 0, 0);
    accA = __builtin_amdgcn_mfma_f32_32x32x16_bf16(alo, bh, accA, 0, 0, 0);

    a0 = b0; a1 = b1; b0 = c0; b1 = c1; c0 = d0; c1 = d1;
    bh = nbh; bl = nbl;
  }

#pragma unroll
  for (int i = 0; i < 16; ++i) accA[i] += accB[i];

  // cross-wave combine: wave1 -> LDS (padded, conflict-free), wave0 adds
  __shared__ float red[64][17];
  if (wv == 1) {
#pragma unroll
    for (int i = 0; i < 16; ++i) red[lane][i] = accA[i];
  }
  __syncthreads();
  if (wv == 0) {
#pragma unroll
    for (int i = 0; i < 16; ++i) accA[i] += red[lane][i];

    // C layout: col(seq)=lane&31, row=(r&3)+8*(r>>2)+4*half
    unsigned long long best = 0ull;
#pragma unroll
    for (int r = 0; r < 16; ++r) {
      int row = (r & 3) + 8 * (r >> 2) + 4 * half;
      int v = tile * 32 + row;
      if (v < VOCAB) {
        unsigned u = __float_as_uint(accA[r]);
        u = (u & 0x80000000u) ? ~u : (u | 0x80000000u);
        unsigned long long key = ((unsigned long long)u << 32) | (unsigned)(~v);
        if (key > best) best = key;
      }
    }
    unsigned long long o = __shfl_xor(best, 32, 64);
    if (o > best) best = o;
    if (half == 0) atomicMax(&gkeys[r32], best);  // lane r32 holds seq r32
  }
}

__global__ void k_final(const unsigned long long* __restrict__ gkeys,
                        int* __restrict__ out) {
  int s = threadIdx.x;
  if (s < NUM_SEQS)
    out[s] = (int)(~(unsigned)(gkeys[s] & 0xFFFFFFFFull));
}

extern "C" void kernel_launch(void* const* d_in, const int* in_sizes, int n_in,
                              void* d_out, int out_size, void* d_ws, size_t ws_size,
                              hipStream_t stream) {
  const float* hs  = (const float*)d_in[0];   // [16384][4096] f32
  const float* W   = (const float*)d_in[1];   // [50257][4096] f32
  const int* lens  = (const int*)d_in[2];     // [32] i32

  char* ws = (char*)d_ws;
  int* idx = (int*)ws;
  unsigned long long* gkeys = (unsigned long long*)(ws + 512);
  short* hBh = (short*)(ws + 4096);
  short* hBl = (short*)(ws + 266240);
  int* out = (int*)d_out;

  k_prep<<<1, 64, 0, stream>>>(lens, idx, gkeys);
  k_gather<<<256, 512, 0, stream>>>(hs, idx, hBh, hBl);
  k_mfma<<<NT, 128, 0, stream>>>(W, hBh, hBl, gkeys);
  k_final<<<1, 64, 0, stream>>>(gkeys, out);
}